// Round 13
// baseline (47.607 us; speedup 1.0000x reference)
//
#include <hip/hip_runtime.h>
#include <float.h>
#include <math.h>

#define TOKENS 8192
#define DIM    4096

typedef _Float16 v8h  __attribute__((ext_vector_type(8)));
typedef float    v4f  __attribute__((ext_vector_type(4)));

typedef __attribute__((address_space(3))) unsigned int lds_uint;
typedef const __attribute__((address_space(1))) unsigned int glob_uint;

__device__ __forceinline__ void stage16(const _Float16* g, _Float16* l) {
    // one instr: 64 lanes x 16 B -> LDS at (wave-uniform base + lane*16)
    __builtin_amdgcn_global_load_lds((glob_uint*)g, (lds_uint*)l, 16, 0, 0);
}

// ---------------------------------------------------------------------------
// Prep: fp16 hi/lo split B-fragments of W in d_ws (2 MB).
// WF[chunk(128)][term(2)][et(4)][lane(64)][8]:
//   B[k][n] with n = et*16 + (lane&15), k = chunk*32 + (lane>>4)*8 + j
// One chunk slab = 4096 halfs = 8 KB, contiguous.
// ---------------------------------------------------------------------------
__global__ __launch_bounds__(256) void prep_w_kernel(
    const float* __restrict__ W, _Float16* __restrict__ WF) {
    int n = blockIdx.x * 256 + threadIdx.x;   // 32768
    int chunk = n >> 8;
    int et    = (n >> 6) & 3;
    int lane  = n & 63;
    int e  = et * 16 + (lane & 15);
    int k0 = chunk * 32 + (lane >> 4) * 8;
    const float* src = W + (size_t)e * DIM + k0;
    v8h h, l;
    #pragma unroll
    for (int j = 0; j < 8; ++j) {
        float w = src[j];
        _Float16 wh = (_Float16)w;
        h[j] = wh;
        l[j] = (_Float16)((w - (float)wh) * 2048.0f);
    }
    size_t base = (size_t)chunk * 4096 + (size_t)et * 512 + (size_t)lane * 8;
    *(v8h*)(WF + base)        = h;
    *(v8h*)(WF + base + 2048) = l;
}

// ---- helpers (all names/indices compile-time) ------------------------------
// A-burst: 4 consecutive chunks = 512 B contiguous per token row, issued
// back-to-back so DRAM sees one large burst (fewer page activations).
#define LOAD_A8(S0a, S0b, S1a, S1b, S2a, S2b, S3a, S3b, cc) do {              \
    const float* ap_ = abase + (cc) * 32;                                     \
    S0a = *(const v4f*)(ap_);        S0b = *(const v4f*)(ap_ + 4);            \
    S1a = *(const v4f*)(ap_ + 32);   S1b = *(const v4f*)(ap_ + 36);           \
    S2a = *(const v4f*)(ap_ + 64);   S2b = *(const v4f*)(ap_ + 68);           \
    S3a = *(const v4f*)(ap_ + 96);   S3b = *(const v4f*)(ap_ + 100);          \
} while (0)

// stage chunk cc's 8 KB slab into buf[BI]; each wave stages its 1 KB portion
#define STAGE(BI, cc) stage16(sbase + (size_t)(cc) * 4096, &buf[BI][wq * 512])

#define CVT1(f, j) {                                                          \
    _Float16 h_ = (_Float16)(f);                                              \
    ah[j] = h_;                                                               \
    al[j] = (_Float16)(((f) - (float)h_) * 2048.0f);                          \
}
#define CVT(Aa, Ab) do {                                                      \
    CVT1(Aa[0], 0) CVT1(Aa[1], 1) CVT1(Aa[2], 2) CVT1(Aa[3], 3)               \
    CVT1(Ab[0], 4) CVT1(Ab[1], 5) CVT1(Ab[2], 6) CVT1(Ab[3], 7)               \
} while (0)

#define MFMA16(a, b, c) __builtin_amdgcn_mfma_f32_16x16x32_f16(a, b, c, 0, 0, 0)

// compute chunk from buf[BI], split into two halves (caps B-frag liveness at
// 16 VGPR): 2x{4 ds_read_b128 + 6 MFMA}
#define COMPC(BI, Aa, Ab) do {                                                \
    CVT(Aa, Ab);                                                              \
    const _Float16* bp_ = &buf[BI][0] + (size_t)lane * 8;                     \
    {                                                                         \
        v8h h0_ = *(const v8h*)(bp_);                                         \
        v8h h1_ = *(const v8h*)(bp_ + 512);                                   \
        v8h l0_ = *(const v8h*)(bp_ + 2048);                                  \
        v8h l1_ = *(const v8h*)(bp_ + 2560);                                  \
        acc1[0] = MFMA16(ah, h0_, acc1[0]);                                   \
        acc1[1] = MFMA16(ah, h1_, acc1[1]);                                   \
        acc2[0] = MFMA16(al, h0_, acc2[0]);  acc2[0] = MFMA16(ah, l0_, acc2[0]); \
        acc2[1] = MFMA16(al, h1_, acc2[1]);  acc2[1] = MFMA16(ah, l1_, acc2[1]); \
    }                                                                         \
    {                                                                         \
        v8h h2_ = *(const v8h*)(bp_ + 1024);                                  \
        v8h h3_ = *(const v8h*)(bp_ + 1536);                                  \
        v8h l2_ = *(const v8h*)(bp_ + 3072);                                  \
        v8h l3_ = *(const v8h*)(bp_ + 3584);                                  \
        acc1[2] = MFMA16(ah, h2_, acc1[2]);                                   \
        acc1[3] = MFMA16(ah, h3_, acc1[3]);                                   \
        acc2[2] = MFMA16(al, h2_, acc2[2]);  acc2[2] = MFMA16(ah, l2_, acc2[2]); \
        acc2[3] = MFMA16(al, h3_, acc2[3]);  acc2[3] = MFMA16(ah, l3_, acc2[3]); \
    }                                                                         \
} while (0)

#define BARRIER_KEEP(n) do {                                                  \
    __builtin_amdgcn_sched_barrier(0);                                        \
    asm volatile("s_waitcnt vmcnt(" #n ")" ::: "memory");                     \
    __builtin_amdgcn_sched_barrier(0);                                        \
    __builtin_amdgcn_s_barrier();                                             \
    __builtin_amdgcn_sched_barrier(0);                                        \
} while (0)

// ---------------------------------------------------------------------------
// Pass 1: partial logits. 512 blocks x 512 thr (8 waves = 8 M-tiles of 16
// tokens -> 128 tokens/block). Block (tg, kg) covers K-slice kg (16 chunks).
// A-loads batched 4 chunks/burst (DRAM page locality); B staged 2-ahead in a
// triple buffer; vmcnt per iteration derived from the in-order queue so
// stages retire with 1 iter of cover and bursts are never stall-retired.
// ---------------------------------------------------------------------------
__global__ __launch_bounds__(512, 4) void logits_kernel(
    const float* __restrict__ x,
    const _Float16* __restrict__ WF,
    float* __restrict__ P) {

    __shared__ _Float16 buf[3][4096];     // 3 x 8 KB triple-buffered B slab

    const int tid  = threadIdx.x;
    const int wq   = tid >> 6;            // wave = M-tile
    const int lane = tid & 63;
    const int kg   = (int)(blockIdx.x & 7);       // K-slice (512 d)
    const int tg   = (int)(blockIdx.x >> 3);      // token group (128 tokens)
    const int tok0 = tg * 128 + wq * 16;
    const int art  = lane & 15;           // token row within M-tile
    const int akg  = lane >> 4;           // k-group
    const int chunk0 = kg * 16;

    const float*    abase = x  + (size_t)(tok0 + art) * DIM + chunk0 * 32 + akg * 8;
    const _Float16* sbase = WF + (size_t)chunk0 * 4096 + (size_t)tid * 8;  // stage src

    v4f acc1[4], acc2[4];
    #pragma unroll
    for (int e4 = 0; e4 < 4; ++e4) { acc1[e4] = (v4f)0.0f; acc2[e4] = (v4f)0.0f; }

    v4f AP0a, AP0b, AP1a, AP1b, AP2a, AP2b, AP3a, AP3b;   // set P
    v4f AQ0a, AQ0b, AQ1a, AQ1b, AQ2a, AQ2b, AQ3a, AQ3b;   // set Q
    v8h ah, al;

    // prologue: S0 first so its retire keeps the bursts in flight; vmcnt(17)
    // retires exactly S0 (queue: S0, A8P, A8Q, S1 = 18).
    STAGE(0, 0);
    LOAD_A8(AP0a, AP0b, AP1a, AP1b, AP2a, AP2b, AP3a, AP3b, 0);
    LOAD_A8(AQ0a, AQ0b, AQ1a, AQ1b, AQ2a, AQ2b, AQ3a, AQ3b, 4);
    STAGE(1, 1);
    BARRIER_KEEP(17);

    // c=0..2: stage 2-ahead; one-time drain of the prologue bursts at c=0
    STAGE(2, 2);  COMPC(0, AP0a, AP0b);  BARRIER_KEEP(1);
    STAGE(0, 3);  COMPC(1, AP1a, AP1b);  BARRIER_KEEP(1);
    STAGE(1, 4);  COMPC(2, AP2a, AP2b);  BARRIER_KEEP(1);
    // c=3: last P chunk consumed, then reload P with chunks 8..11
    STAGE(2, 5);  COMPC(0, AP3a, AP3b);
    LOAD_A8(AP0a, AP0b, AP1a, AP1b, AP2a, AP2b, AP3a, AP3b, 8);
    BARRIER_KEEP(9);
    // c=4..6
    STAGE(0, 6);  COMPC(1, AQ0a, AQ0b);  BARRIER_KEEP(9);
    STAGE(1, 7);  COMPC(2, AQ1a, AQ1b);  BARRIER_KEEP(1);   // drains A8P (2 iters old)
    STAGE(2, 8);  COMPC(0, AQ2a, AQ2b);  BARRIER_KEEP(1);
    // c=7: last Q chunk consumed, then reload Q with chunks 12..15
    STAGE(0, 9);  COMPC(1, AQ3a, AQ3b);
    LOAD_A8(AQ0a, AQ0b, AQ1a, AQ1b, AQ2a, AQ2b, AQ3a, AQ3b, 12);
    BARRIER_KEEP(9);
    // c=8..11
    STAGE(1, 10); COMPC(2, AP0a, AP0b);  BARRIER_KEEP(9);
    STAGE(2, 11); COMPC(0, AP1a, AP1b);  BARRIER_KEEP(1);   // drains A8Q (2 iters old)
    STAGE(0, 12); COMPC(1, AP2a, AP2b);  BARRIER_KEEP(1);
    STAGE(1, 13); COMPC(2, AP3a, AP3b);  BARRIER_KEEP(1);
    // c=12..15 (no more bursts; chunks 12-15 live in Q)
    STAGE(2, 14); COMPC(0, AQ0a, AQ0b);  BARRIER_KEEP(1);
    STAGE(0, 15); COMPC(1, AQ1a, AQ1b);  BARRIER_KEEP(1);
    COMPC(2, AQ2a, AQ2b);                BARRIER_KEEP(0);
    COMPC(0, AQ3a, AQ3b);

    // write partial logits: C/D layout col=lane&15(expert), row=(lane>>4)*4+r
    const float inv2048 = 1.0f / 2048.0f;
    #pragma unroll
    for (int e4 = 0; e4 < 4; ++e4) {
        #pragma unroll
        for (int r = 0; r < 4; ++r) {
            float v = acc1[e4][r] + acc2[e4][r] * inv2048;
            P[((size_t)kg * TOKENS + tok0 + akg * 4 + r) * 64 + e4 * 16 + art] = v;
        }
    }
}

// ---------------------------------------------------------------------------
// Pass 2: logits = sum of 8 K-slice partials; top-2 + gates. 512 x 256.
// ---------------------------------------------------------------------------
__global__ __launch_bounds__(256) void reduce_topk_kernel(
    const float* __restrict__ P, float* __restrict__ out) {
    const int wq   = threadIdx.x >> 6;
    const int lane = threadIdx.x & 63;
    #pragma unroll
    for (int tt = 0; tt < 4; ++tt) {
        int gt = blockIdx.x * 16 + wq * 4 + tt;
        float v = 0.f;
        #pragma unroll
        for (int kg = 0; kg < 8; ++kg)
            v += P[((size_t)kg * TOKENS + gt) * 64 + lane];

        // argmax #1 (tie-break: smaller index, matching jax.lax.top_k)
        float bv = v; int bi = lane;
        #pragma unroll
        for (int off = 32; off >= 1; off >>= 1) {
            float ov = __shfl_xor(bv, off);
            int   oi = __shfl_xor(bi, off);
            if (ov > bv || (ov == bv && oi < bi)) { bv = ov; bi = oi; }
        }
        // argmax #2 (exclude bi)
        float v2 = (lane == bi) ? -FLT_MAX : v;
        float bv2 = v2; int bi2 = lane;
        #pragma unroll
        for (int off = 32; off >= 1; off >>= 1) {
            float ov = __shfl_xor(bv2, off);
            int   oi = __shfl_xor(bi2, off);
            if (ov > bv2 || (ov == bv2 && oi < bi2)) { bv2 = ov; bi2 = oi; }
        }

        if (lane == 0) {
            // top-2 renormalized softmax cancels: g0 = 1/(1+exp(l1-l0))
            float g0 = 1.0f / (1.0f + expf(bv2 - bv));
            out[gt]              = (float)bi;
            out[TOKENS + gt]     = (float)bi2;
            out[2 * TOKENS + gt] = g0;
            out[3 * TOKENS + gt] = 1.0f - g0;
        }
    }
}

extern "C" void kernel_launch(void* const* d_in, const int* in_sizes, int n_in,
                              void* d_out, int out_size, void* d_ws, size_t ws_size,
                              hipStream_t stream) {
    const float* x = (const float*)d_in[0];   // [8192, 4096] fp32
    const float* W = (const float*)d_in[1];   // [64, 4096] fp32
    float* out     = (float*)d_out;           // [4 * 8192] fp32
    _Float16* WF   = (_Float16*)d_ws;                     // 2 MB fragments
    float* P       = (float*)((char*)d_ws + (2 << 20));   // 16 MB partials

    prep_w_kernel<<<128, 256, 0, stream>>>(W, WF);
    logits_kernel<<<512, 512, 0, stream>>>(x, WF, P);
    reduce_topk_kernel<<<512, 256, 0, stream>>>(P, out);
}

// Round 14
// 43.243 us; speedup vs baseline: 1.1009x; 1.1009x over previous
//
#include <hip/hip_runtime.h>
#include <float.h>
#include <math.h>

#define TOKENS 8192
#define DIM    4096

typedef _Float16 v8h  __attribute__((ext_vector_type(8)));
typedef float    v4f  __attribute__((ext_vector_type(4)));

typedef __attribute__((address_space(3))) unsigned int lds_uint;
typedef const __attribute__((address_space(1))) unsigned int glob_uint;

__device__ __forceinline__ void stage16(const _Float16* g, _Float16* l) {
    // one instr: 64 lanes x 16 B -> LDS at (wave-uniform base + lane*16)
    __builtin_amdgcn_global_load_lds((glob_uint*)g, (lds_uint*)l, 16, 0, 0);
}

// ---------------------------------------------------------------------------
// Prep: fp16 hi/lo split B-fragments of W in d_ws (1 MB).
// WF[chunk(128)][term(2)][et(4)][lane(64)][8]:
//   B[k][n] with n = et*16 + (lane&15), k = chunk*32 + (lane>>4)*8 + j
// One chunk slab = 4096 halfs = 8 KB, contiguous; 2 chunks = 16 KB slab.
// ---------------------------------------------------------------------------
__global__ __launch_bounds__(256) void prep_w_kernel(
    const float* __restrict__ W, _Float16* __restrict__ WF) {
    int n = blockIdx.x * 256 + threadIdx.x;   // 32768
    int chunk = n >> 8;
    int et    = (n >> 6) & 3;
    int lane  = n & 63;
    int e  = et * 16 + (lane & 15);
    int k0 = chunk * 32 + (lane >> 4) * 8;
    const float* src = W + (size_t)e * DIM + k0;
    v8h h, l;
    #pragma unroll
    for (int j = 0; j < 8; ++j) {
        float w = src[j];
        _Float16 wh = (_Float16)w;
        h[j] = wh;
        l[j] = (_Float16)((w - (float)wh) * 2048.0f);
    }
    size_t base = (size_t)chunk * 4096 + (size_t)et * 512 + (size_t)lane * 8;
    *(v8h*)(WF + base)        = h;
    *(v8h*)(WF + base + 2048) = l;
}

// ---- helpers (all names/indices compile-time) ------------------------------
// A for 2 chunks (local chunk j, j+1): 4 x v4f per lane
#define LOAD_A4(A0a, A0b, A1a, A1b, jj) do {                                  \
    const float* ap_ = abase + (jj) * 32;                                     \
    A0a = *(const v4f*)(ap_);       A0b = *(const v4f*)(ap_ + 4);             \
    A1a = *(const v4f*)(ap_ + 32);  A1b = *(const v4f*)(ap_ + 36);            \
} while (0)

// stage 2-chunk slab (16 KB) into buf[BI]; each wave stages its 2 KB portion
#define STAGE2(BI, jj) do {                                                   \
    stage16(sbase + (size_t)(jj) * 4096,       &buf[BI][wq * 1024]);          \
    stage16(sbase + (size_t)(jj) * 4096 + 512, &buf[BI][wq * 1024 + 512]);    \
} while (0)

#define CVT1(f, j) {                                                          \
    _Float16 h_ = (_Float16)(f);                                              \
    ah[j] = h_;                                                               \
    al[j] = (_Float16)(((f) - (float)h_) * 2048.0f);                          \
}
#define CVT(Aa, Ab) do {                                                      \
    CVT1(Aa[0], 0) CVT1(Aa[1], 1) CVT1(Aa[2], 2) CVT1(Aa[3], 3)               \
    CVT1(Ab[0], 4) CVT1(Ab[1], 5) CVT1(Ab[2], 6) CVT1(Ab[3], 7)               \
} while (0)

#define MFMA16(a, b, c) __builtin_amdgcn_mfma_f32_16x16x32_f16(a, b, c, 0, 0, 0)

// compute one chunk from buf[BI] at half-offset COFF (0 or 4096):
// 8 conflict-free ds_read_b128 + 12 MFMA
#define COMPC(BI, COFF, Aa, Ab) do {                                          \
    CVT(Aa, Ab);                                                              \
    const _Float16* bp_ = &buf[BI][COFF] + (size_t)lane * 8;                  \
    v8h h0_ = *(const v8h*)(bp_);                                             \
    v8h h1_ = *(const v8h*)(bp_ + 512);                                       \
    v8h h2_ = *(const v8h*)(bp_ + 1024);                                      \
    v8h h3_ = *(const v8h*)(bp_ + 1536);                                      \
    v8h l0_ = *(const v8h*)(bp_ + 2048);                                      \
    v8h l1_ = *(const v8h*)(bp_ + 2560);                                      \
    v8h l2_ = *(const v8h*)(bp_ + 3072);                                      \
    v8h l3_ = *(const v8h*)(bp_ + 3584);                                      \
    acc1[0] = MFMA16(ah, h0_, acc1[0]);                                       \
    acc1[1] = MFMA16(ah, h1_, acc1[1]);                                       \
    acc1[2] = MFMA16(ah, h2_, acc1[2]);                                       \
    acc1[3] = MFMA16(ah, h3_, acc1[3]);                                       \
    acc2[0] = MFMA16(al, h0_, acc2[0]);  acc2[0] = MFMA16(ah, l0_, acc2[0]);  \
    acc2[1] = MFMA16(al, h1_, acc2[1]);  acc2[1] = MFMA16(ah, l1_, acc2[1]);  \
    acc2[2] = MFMA16(al, h2_, acc2[2]);  acc2[2] = MFMA16(ah, l2_, acc2[2]);  \
    acc2[3] = MFMA16(al, h3_, acc2[3]);  acc2[3] = MFMA16(ah, l3_, acc2[3]);  \
} while (0)

#define BARRIER_KEEP(n) do {                                                  \
    __builtin_amdgcn_sched_barrier(0);                                        \
    asm volatile("s_waitcnt vmcnt(" #n ")" ::: "memory");                     \
    __builtin_amdgcn_sched_barrier(0);                                        \
    __builtin_amdgcn_s_barrier();                                             \
    __builtin_amdgcn_sched_barrier(0);                                        \
} while (0)

// iteration i (chunks 2i, 2i+1) consuming buf[i%3] and A-set S(i%2):
// issue order per iter: STAGE2(i+2) | compute 2 chunks | LOAD_A4(i+2) into the
// set just consumed | barrier vmcnt(10) = retire exactly stage(i+1), keep
// stage(i+2)x2 + A(i+2)x4 in flight. A-use waits are compiler-tracked.
#define ITER_FULL(i, BI, BN, Ac0a, Ac0b, Ac1a, Ac1b) do {                     \
    STAGE2(BN, 2 * (i) + 4);                                                  \
    COMPC(BI, 0,    Ac0a, Ac0b);                                              \
    COMPC(BI, 4096, Ac1a, Ac1b);                                              \
    LOAD_A4(Ac0a, Ac0b, Ac1a, Ac1b, 2 * (i) + 4);                             \
    BARRIER_KEEP(10);                                                         \
} while (0)

// ---------------------------------------------------------------------------
// Pass 1: partial logits. 512 blocks x 512 thr (8 waves = 8 M-tiles of 16
// tokens -> 128 tokens/block). Block (tg, kg) covers K-slice kg (16 chunks =
// 8 iterations of 2 chunks). kg == XCD under %8 round-robin dispatch so each
// XCD keeps its 128 KB WF slice L2-resident.
// ---------------------------------------------------------------------------
__global__ __launch_bounds__(512, 4) void logits_kernel(
    const float* __restrict__ x,
    const _Float16* __restrict__ WF,
    float* __restrict__ P) {

    __shared__ _Float16 buf[3][8192];     // 3 x 16 KB triple-buffered B slab

    const int tid  = threadIdx.x;
    const int wq   = tid >> 6;            // wave = M-tile
    const int lane = tid & 63;
    const int kg   = (int)(blockIdx.x & 7);       // K-slice (512 d)
    const int tg   = (int)(blockIdx.x >> 3);      // token group (128 tokens)
    const int tok0 = tg * 128 + wq * 16;
    const int art  = lane & 15;           // token row within M-tile
    const int akg  = lane >> 4;           // k-group
    const int chunk0 = kg * 16;

    const float*    abase = x  + (size_t)(tok0 + art) * DIM + chunk0 * 32 + akg * 8;
    const _Float16* sbase = WF + (size_t)chunk0 * 4096 + wq * 1024 + lane * 8;

    v4f acc1[4], acc2[4];
    #pragma unroll
    for (int e4 = 0; e4 < 4; ++e4) { acc1[e4] = (v4f)0.0f; acc2[e4] = (v4f)0.0f; }

    v4f S0c0a, S0c0b, S0c1a, S0c1b;       // A set 0 (even iters)
    v4f S1c0a, S1c0b, S1c1a, S1c1b;       // A set 1 (odd iters)
    v8h ah, al;

    // prologue: st(0)->buf0, A(iter0), st(1)->buf1, A(iter1).
    // vmcnt(10) retires exactly st(0) (younger: A0 x4 + st1 x2 + A1 x4).
    STAGE2(0, 0);
    LOAD_A4(S0c0a, S0c0b, S0c1a, S0c1b, 0);
    STAGE2(1, 2);
    LOAD_A4(S1c0a, S1c0b, S1c1a, S1c1b, 2);
    BARRIER_KEEP(10);

    ITER_FULL(0, 0, 2, S0c0a, S0c0b, S0c1a, S0c1b);
    ITER_FULL(1, 1, 0, S1c0a, S1c0b, S1c1a, S1c1b);
    ITER_FULL(2, 2, 1, S0c0a, S0c0b, S0c1a, S0c1b);
    ITER_FULL(3, 0, 2, S1c0a, S1c0b, S1c1a, S1c1b);
    ITER_FULL(4, 1, 0, S0c0a, S0c0b, S0c1a, S0c1b);
    ITER_FULL(5, 2, 1, S1c0a, S1c0b, S1c1a, S1c1b);
    // iter 6 (chunks 12,13; buf0): nothing left to issue; retire st(7)
    // (issued iter-5 start; younger = A(7) x4) -> vmcnt(4)
    COMPC(0, 0,    S0c0a, S0c0b);
    COMPC(0, 4096, S0c1a, S0c1b);
    BARRIER_KEEP(4);
    // iter 7 (chunks 14,15; buf1): final, no barrier
    COMPC(1, 0,    S1c0a, S1c0b);
    COMPC(1, 4096, S1c1a, S1c1b);

    // write partial logits: C/D layout col=lane&15(expert), row=(lane>>4)*4+r
    const float inv2048 = 1.0f / 2048.0f;
    #pragma unroll
    for (int e4 = 0; e4 < 4; ++e4) {
        #pragma unroll
        for (int r = 0; r < 4; ++r) {
            float v = acc1[e4][r] + acc2[e4][r] * inv2048;
            P[((size_t)kg * TOKENS + tok0 + akg * 4 + r) * 64 + e4 * 16 + art] = v;
        }
    }
}

// ---------------------------------------------------------------------------
// Pass 2: logits = sum of 8 K-slice partials; top-2 + gates. 512 x 256.
// ---------------------------------------------------------------------------
__global__ __launch_bounds__(256) void reduce_topk_kernel(
    const float* __restrict__ P, float* __restrict__ out) {
    const int wq   = threadIdx.x >> 6;
    const int lane = threadIdx.x & 63;
    #pragma unroll
    for (int tt = 0; tt < 4; ++tt) {
        int gt = blockIdx.x * 16 + wq * 4 + tt;
        float v = 0.f;
        #pragma unroll
        for (int kg = 0; kg < 8; ++kg)
            v += P[((size_t)kg * TOKENS + gt) * 64 + lane];

        // argmax #1 (tie-break: smaller index, matching jax.lax.top_k)
        float bv = v; int bi = lane;
        #pragma unroll
        for (int off = 32; off >= 1; off >>= 1) {
            float ov = __shfl_xor(bv, off);
            int   oi = __shfl_xor(bi, off);
            if (ov > bv || (ov == bv && oi < bi)) { bv = ov; bi = oi; }
        }
        // argmax #2 (exclude bi)
        float v2 = (lane == bi) ? -FLT_MAX : v;
        float bv2 = v2; int bi2 = lane;
        #pragma unroll
        for (int off = 32; off >= 1; off >>= 1) {
            float ov = __shfl_xor(bv2, off);
            int   oi = __shfl_xor(bi2, off);
            if (ov > bv2 || (ov == bv2 && oi < bi2)) { bv2 = ov; bi2 = oi; }
        }

        if (lane == 0) {
            // top-2 renormalized softmax cancels: g0 = 1/(1+exp(l1-l0))
            float g0 = 1.0f / (1.0f + expf(bv2 - bv));
            out[gt]              = (float)bi;
            out[TOKENS + gt]     = (float)bi2;
            out[2 * TOKENS + gt] = g0;
            out[3 * TOKENS + gt] = 1.0f - g0;
        }
    }
}

extern "C" void kernel_launch(void* const* d_in, const int* in_sizes, int n_in,
                              void* d_out, int out_size, void* d_ws, size_t ws_size,
                              hipStream_t stream) {
    const float* x = (const float*)d_in[0];   // [8192, 4096] fp32
    const float* W = (const float*)d_in[1];   // [64, 4096] fp32
    float* out     = (float*)d_out;           // [4 * 8192] fp32
    _Float16* WF   = (_Float16*)d_ws;                     // 1 MB fragments
    float* P       = (float*)((char*)d_ws + (1 << 20));   // 16 MB partials

    prep_w_kernel<<<128, 256, 0, stream>>>(W, WF);
    logits_kernel<<<512, 512, 0, stream>>>(x, WF, P);
    reduce_topk_kernel<<<512, 256, 0, stream>>>(P, out);
}

// Round 16
// 41.188 us; speedup vs baseline: 1.1558x; 1.0499x over previous
//
#include <hip/hip_runtime.h>
#include <float.h>
#include <math.h>

#define TOKENS 8192
#define DIM    4096

typedef _Float16 v8h  __attribute__((ext_vector_type(8)));
typedef float    v4f  __attribute__((ext_vector_type(4)));

typedef __attribute__((address_space(3))) unsigned int lds_uint;
typedef const __attribute__((address_space(1))) unsigned int glob_uint;

__device__ __forceinline__ void stage16(const _Float16* g, _Float16* l) {
    // one instr: 64 lanes x 16 B -> LDS at (wave-uniform base + lane*16)
    __builtin_amdgcn_global_load_lds((glob_uint*)g, (lds_uint*)l, 16, 0, 0);
}

// ---------------------------------------------------------------------------
// Prep: fp16 hi/lo split B-fragments of W in d_ws (1 MB).
// WF[chunk(128)][term(2)][et(4)][lane(64)][8]:
//   B[k][n] with n = et*16 + (lane&15), k = chunk*32 + (lane>>4)*8 + j
// One chunk slab = 4096 halfs = 8 KB, contiguous.
// ---------------------------------------------------------------------------
__global__ __launch_bounds__(256) void prep_w_kernel(
    const float* __restrict__ W, _Float16* __restrict__ WF) {
    int n = blockIdx.x * 256 + threadIdx.x;   // 32768
    int chunk = n >> 8;
    int et    = (n >> 6) & 3;
    int lane  = n & 63;
    int e  = et * 16 + (lane & 15);
    int k0 = chunk * 32 + (lane >> 4) * 8;
    const float* src = W + (size_t)e * DIM + k0;
    v8h h, l;
    #pragma unroll
    for (int j = 0; j < 8; ++j) {
        float w = src[j];
        _Float16 wh = (_Float16)w;
        h[j] = wh;
        l[j] = (_Float16)((w - (float)wh) * 2048.0f);
    }
    size_t base = (size_t)chunk * 4096 + (size_t)et * 512 + (size_t)lane * 8;
    *(v8h*)(WF + base)        = h;
    *(v8h*)(WF + base + 2048) = l;
}

// ---- helpers (all names/indices compile-time) ------------------------------
// A for one chunk, BOTH M-frags (2 x 8 floats per lane)
#define LOAD_A4(A0a, A0b, A1a, A1b, cc) do {                                  \
    const float* a0_ = abase0 + (cc) * 32;                                    \
    const float* a1_ = abase1 + (cc) * 32;                                    \
    A0a = *(const v4f*)(a0_);  A0b = *(const v4f*)(a0_ + 4);                  \
    A1a = *(const v4f*)(a1_);  A1b = *(const v4f*)(a1_ + 4);                  \
} while (0)

// stage chunk cc's 8 KB slab into buf[BI]; each of 4 waves stages 2 KB
#define STAGE(BI, cc) do {                                                    \
    stage16(sbase + (size_t)(cc) * 4096,       &buf[BI][wq * 1024]);          \
    stage16(sbase + (size_t)(cc) * 4096 + 512, &buf[BI][wq * 1024 + 512]);    \
} while (0)

#define CVT1(dsth, dstl, f, j) {                                              \
    _Float16 h_ = (_Float16)(f);                                              \
    dsth[j] = h_;                                                             \
    dstl[j] = (_Float16)(((f) - (float)h_) * 2048.0f);                        \
}
#define CVT(dsth, dstl, Aa, Ab) do {                                          \
    CVT1(dsth, dstl, Aa[0], 0) CVT1(dsth, dstl, Aa[1], 1)                     \
    CVT1(dsth, dstl, Aa[2], 2) CVT1(dsth, dstl, Aa[3], 3)                     \
    CVT1(dsth, dstl, Ab[0], 4) CVT1(dsth, dstl, Ab[1], 5)                     \
    CVT1(dsth, dstl, Ab[2], 6) CVT1(dsth, dstl, Ab[3], 7)                     \
} while (0)

#define MFMA16(a, b, c) __builtin_amdgcn_mfma_f32_16x16x32_f16(a, b, c, 0, 0, 0)

// compute chunk from buf[BI] for BOTH M-frags: 8 ds_read_b128 + 24 MFMA
// (each B-frag read feeds 6 MFMA -> per-CU LDS read traffic halved)
#define COMPC(BI, A0a, A0b, A1a, A1b) do {                                    \
    CVT(ah0, al0, A0a, A0b);                                                  \
    CVT(ah1, al1, A1a, A1b);                                                  \
    const _Float16* bp_ = &buf[BI][0] + (size_t)lane * 8;                     \
    _Pragma("unroll")                                                         \
    for (int e4_ = 0; e4_ < 4; ++e4_) {                                       \
        v8h h_ = *(const v8h*)(bp_ + e4_ * 512);                              \
        v8h l_ = *(const v8h*)(bp_ + 2048 + e4_ * 512);                       \
        acc1[e4_] = MFMA16(ah0, h_, acc1[e4_]);                               \
        acc3[e4_] = MFMA16(ah1, h_, acc3[e4_]);                               \
        acc2[e4_] = MFMA16(al0, h_, acc2[e4_]);                               \
        acc2[e4_] = MFMA16(ah0, l_, acc2[e4_]);                               \
        acc4[e4_] = MFMA16(al1, h_, acc4[e4_]);                               \
        acc4[e4_] = MFMA16(ah1, l_, acc4[e4_]);                               \
    }                                                                         \
} while (0)

#define BARRIER_KEEP(n) do {                                                  \
    __builtin_amdgcn_sched_barrier(0);                                        \
    asm volatile("s_waitcnt vmcnt(" #n ")" ::: "memory");                     \
    __builtin_amdgcn_sched_barrier(0);                                        \
    __builtin_amdgcn_s_barrier();                                             \
    __builtin_amdgcn_sched_barrier(0);                                        \
} while (0)

// full iter: stage B(c+2) 2-ahead; COMPUTE chunk c FIRST; then reload the
// just-consumed A set with chunk c+2 (register-dep waits make this safe —
// the round-15 bug was load-before-compute into the same set).
// vmcnt(10) at the barrier retires EXACTLY stage(c+1): younger ops are
// A(c+1)x4 + st(c+2)x2 + A(c+2)x4 = 10. A-use waits are compiler-tracked.
#define ITER_FULL(c, BI, BN, Ac0a, Ac0b, Ac1a, Ac1b) do {                     \
    STAGE(BN, (c) + 2);                                                       \
    COMPC(BI, Ac0a, Ac0b, Ac1a, Ac1b);                                        \
    LOAD_A4(Ac0a, Ac0b, Ac1a, Ac1b, (c) + 2);                                 \
    BARRIER_KEEP(10);                                                         \
} while (0)

// ---------------------------------------------------------------------------
// Pass 1: partial logits. 512 blocks x 256 thr (4 waves). Each wave owns a
// 32-token x 64-expert output tile (2 M-frags) -> wave count halved vs the
// 16-token tile, halving per-CU LDS read traffic. Block = 128 tokens,
// K-slice kg (16 chunks); B slab triple-buffered, staged 2-ahead.
// ---------------------------------------------------------------------------
__global__ __launch_bounds__(256, 2) void logits_kernel(
    const float* __restrict__ x,
    const _Float16* __restrict__ WF,
    float* __restrict__ P) {

    __shared__ _Float16 buf[3][4096];     // 3 x 8 KB triple-buffered B slab

    const int tid  = threadIdx.x;
    const int wq   = tid >> 6;            // wave -> 32-token supertile
    const int lane = tid & 63;
    const int kg   = (int)(blockIdx.x & 7);       // K-slice (512 d)
    const int tg   = (int)(blockIdx.x >> 3);      // token group (128 tokens)
    const int tokB = tg * 128 + wq * 32;  // wave's first token
    const int art  = lane & 15;           // token row within M-frag
    const int akg  = lane >> 4;           // k-group
    const int chunk0 = kg * 16;

    const float* abase0 = x + (size_t)(tokB + art) * DIM      + chunk0 * 32 + akg * 8;
    const float* abase1 = x + (size_t)(tokB + 16 + art) * DIM + chunk0 * 32 + akg * 8;
    const _Float16* sbase = WF + (size_t)chunk0 * 4096 + wq * 1024 + lane * 8;

    v4f acc1[4], acc2[4], acc3[4], acc4[4];
    #pragma unroll
    for (int e4 = 0; e4 < 4; ++e4) {
        acc1[e4] = (v4f)0.0f; acc2[e4] = (v4f)0.0f;
        acc3[e4] = (v4f)0.0f; acc4[e4] = (v4f)0.0f;
    }

    v4f S0a, S0b, S0c, S0d;               // A set 0 (even chunks): frag0, frag1
    v4f S1a, S1b, S1c, S1d;               // A set 1 (odd chunks)
    v8h ah0, al0, ah1, al1;

    // prologue: st(0), A(0), st(1), A(1). Ops younger than st(0) = A(0)x4 +
    // st(1)x2 + A(1)x4 = 10 -> vmcnt(10) retires exactly st(0).
    STAGE(0, 0);
    LOAD_A4(S0a, S0b, S0c, S0d, 0);
    STAGE(1, 1);
    LOAD_A4(S1a, S1b, S1c, S1d, 1);
    BARRIER_KEEP(10);

    ITER_FULL(0,  0, 2, S0a, S0b, S0c, S0d);   // computes chunk 0, reloads S0<-2
    ITER_FULL(1,  1, 0, S1a, S1b, S1c, S1d);
    ITER_FULL(2,  2, 1, S0a, S0b, S0c, S0d);
    ITER_FULL(3,  0, 2, S1a, S1b, S1c, S1d);
    ITER_FULL(4,  1, 0, S0a, S0b, S0c, S0d);
    ITER_FULL(5,  2, 1, S1a, S1b, S1c, S1d);
    ITER_FULL(6,  0, 2, S0a, S0b, S0c, S0d);
    ITER_FULL(7,  1, 0, S1a, S1b, S1c, S1d);
    ITER_FULL(8,  2, 1, S0a, S0b, S0c, S0d);
    ITER_FULL(9,  0, 2, S1a, S1b, S1c, S1d);
    ITER_FULL(10, 1, 0, S0a, S0b, S0c, S0d);
    ITER_FULL(11, 2, 1, S1a, S1b, S1c, S1d);
    ITER_FULL(12, 0, 2, S0a, S0b, S0c, S0d);   // reloads S0 <- chunk 14
    ITER_FULL(13, 1, 0, S1a, S1b, S1c, S1d);   // stages chunk 15 -> buf0; S1 <- 15
    // c=14 (buf2, S0): compiler wait for A(14) auto-retires to vmcnt(6);
    // barrier must retire st(15): younger = A(15)x4 -> vmcnt(4)
    COMPC(2, S0a, S0b, S0c, S0d);
    BARRIER_KEEP(4);
    // c=15 (buf0, S1): final, no barrier
    COMPC(0, S1a, S1b, S1c, S1d);

    // write partial logits, both M-frags:
    // C/D layout: col(expert) = lane&15, row = (lane>>4)*4 + r
    const float inv2048 = 1.0f / 2048.0f;
    #pragma unroll
    for (int e4 = 0; e4 < 4; ++e4) {
        #pragma unroll
        for (int r = 0; r < 4; ++r) {
            float v0 = acc1[e4][r] + acc2[e4][r] * inv2048;
            float v1 = acc3[e4][r] + acc4[e4][r] * inv2048;
            P[((size_t)kg * TOKENS + tokB + akg * 4 + r) * 64 + e4 * 16 + art]      = v0;
            P[((size_t)kg * TOKENS + tokB + 16 + akg * 4 + r) * 64 + e4 * 16 + art] = v1;
        }
    }
}

// ---------------------------------------------------------------------------
// Pass 2: logits = sum of 8 K-slice partials; top-2 + gates. 512 x 256.
// ---------------------------------------------------------------------------
__global__ __launch_bounds__(256) void reduce_topk_kernel(
    const float* __restrict__ P, float* __restrict__ out) {
    const int wq   = threadIdx.x >> 6;
    const int lane = threadIdx.x & 63;
    #pragma unroll
    for (int tt = 0; tt < 4; ++tt) {
        int gt = blockIdx.x * 16 + wq * 4 + tt;
        float v = 0.f;
        #pragma unroll
        for (int kg = 0; kg < 8; ++kg)
            v += P[((size_t)kg * TOKENS + gt) * 64 + lane];

        // argmax #1 (tie-break: smaller index, matching jax.lax.top_k)
        float bv = v; int bi = lane;
        #pragma unroll
        for (int off = 32; off >= 1; off >>= 1) {
            float ov = __shfl_xor(bv, off);
            int   oi = __shfl_xor(bi, off);
            if (ov > bv || (ov == bv && oi < bi)) { bv = ov; bi = oi; }
        }
        // argmax #2 (exclude bi)
        float v2 = (lane == bi) ? -FLT_MAX : v;
        float bv2 = v2; int bi2 = lane;
        #pragma unroll
        for (int off = 32; off >= 1; off >>= 1) {
            float ov = __shfl_xor(bv2, off);
            int   oi = __shfl_xor(bi2, off);
            if (ov > bv2 || (ov == bv2 && oi < bi2)) { bv2 = ov; bi2 = oi; }
        }

        if (lane == 0) {
            // top-2 renormalized softmax cancels: g0 = 1/(1+exp(l1-l0))
            float g0 = 1.0f / (1.0f + expf(bv2 - bv));
            out[gt]              = (float)bi;
            out[TOKENS + gt]     = (float)bi2;
            out[2 * TOKENS + gt] = g0;
            out[3 * TOKENS + gt] = 1.0f - g0;
        }
    }
}

extern "C" void kernel_launch(void* const* d_in, const int* in_sizes, int n_in,
                              void* d_out, int out_size, void* d_ws, size_t ws_size,
                              hipStream_t stream) {
    const float* x = (const float*)d_in[0];   // [8192, 4096] fp32
    const float* W = (const float*)d_in[1];   // [64, 4096] fp32
    float* out     = (float*)d_out;           // [4 * 8192] fp32
    _Float16* WF   = (_Float16*)d_ws;                     // 1 MB fragments
    float* P       = (float*)((char*)d_ws + (1 << 20));   // 16 MB partials

    prep_w_kernel<<<128, 256, 0, stream>>>(W, WF);
    logits_kernel<<<512, 256, 0, stream>>>(x, WF, P);
    reduce_topk_kernel<<<512, 256, 0, stream>>>(P, out);
}

// Round 17
// 40.393 us; speedup vs baseline: 1.1786x; 1.0197x over previous
//
#include <hip/hip_runtime.h>
#include <float.h>
#include <math.h>

#define TOKENS 8192
#define DIM    4096

typedef _Float16 v8h  __attribute__((ext_vector_type(8)));
typedef float    v4f  __attribute__((ext_vector_type(4)));

typedef __attribute__((address_space(3))) unsigned int lds_uint;
typedef const __attribute__((address_space(1))) unsigned int glob_uint;

__device__ __forceinline__ void stage16(const _Float16* g, _Float16* l) {
    // one instr: 64 lanes x 16 B -> LDS at (wave-uniform base + lane*16)
    __builtin_amdgcn_global_load_lds((glob_uint*)g, (lds_uint*)l, 16, 0, 0);
}

// ---------------------------------------------------------------------------
// Prep: fp16 hi/lo split B-fragments of W in d_ws (1 MB).
// WF[chunk(128)][term(2)][et(4)][lane(64)][8]:
//   B[k][n] with n = et*16 + (lane&15), k = chunk*32 + (lane>>4)*8 + j
// One chunk slab = 4096 halfs = 8 KB, contiguous.
// ---------------------------------------------------------------------------
__global__ __launch_bounds__(256) void prep_w_kernel(
    const float* __restrict__ W, _Float16* __restrict__ WF) {
    int n = blockIdx.x * 256 + threadIdx.x;   // 32768
    int chunk = n >> 8;
    int et    = (n >> 6) & 3;
    int lane  = n & 63;
    int e  = et * 16 + (lane & 15);
    int k0 = chunk * 32 + (lane >> 4) * 8;
    const float* src = W + (size_t)e * DIM + k0;
    v8h h, l;
    #pragma unroll
    for (int j = 0; j < 8; ++j) {
        float w = src[j];
        _Float16 wh = (_Float16)w;
        h[j] = wh;
        l[j] = (_Float16)((w - (float)wh) * 2048.0f);
    }
    size_t base = (size_t)chunk * 4096 + (size_t)et * 512 + (size_t)lane * 8;
    *(v8h*)(WF + base)        = h;
    *(v8h*)(WF + base + 2048) = l;
}

// ---- helpers (all names/indices compile-time) ------------------------------
#define LOAD_A(Aa, Ab, cc) do {                                               \
    const float* ap_ = abase + (cc) * 32;                                     \
    Aa = *(const v4f*)ap_;                                                    \
    Ab = *(const v4f*)(ap_ + 4);                                              \
} while (0)

// stage chunk cc's 8 KB slab into buf[BI]; each wave stages its 1 KB portion
#define STAGE(BI, cc) stage16(sbase + (size_t)(cc) * 4096, &buf[BI][wq * 512])

#define CVT1(f, j) {                                                          \
    _Float16 h_ = (_Float16)(f);                                              \
    ah[j] = h_;                                                               \
    al[j] = (_Float16)(((f) - (float)h_) * 2048.0f);                          \
}
#define CVT(Aa, Ab) do {                                                      \
    CVT1(Aa[0], 0) CVT1(Aa[1], 1) CVT1(Aa[2], 2) CVT1(Aa[3], 3)               \
    CVT1(Ab[0], 4) CVT1(Ab[1], 5) CVT1(Ab[2], 6) CVT1(Ab[3], 7)               \
} while (0)

#define MFMA16(a, b, c) __builtin_amdgcn_mfma_f32_16x16x32_f16(a, b, c, 0, 0, 0)

// compute chunk from buf[BI]: 8 conflict-free ds_read_b128 + 12 MFMA
#define COMPC(BI, Aa, Ab) do {                                                \
    CVT(Aa, Ab);                                                              \
    const _Float16* bp_ = &buf[BI][0] + (size_t)lane * 8;                     \
    v8h h0_ = *(const v8h*)(bp_);                                             \
    v8h h1_ = *(const v8h*)(bp_ + 512);                                       \
    v8h h2_ = *(const v8h*)(bp_ + 1024);                                      \
    v8h h3_ = *(const v8h*)(bp_ + 1536);                                      \
    v8h l0_ = *(const v8h*)(bp_ + 2048);                                      \
    v8h l1_ = *(const v8h*)(bp_ + 2560);                                      \
    v8h l2_ = *(const v8h*)(bp_ + 3072);                                      \
    v8h l3_ = *(const v8h*)(bp_ + 3584);                                      \
    acc1[0] = MFMA16(ah, h0_, acc1[0]);                                       \
    acc1[1] = MFMA16(ah, h1_, acc1[1]);                                       \
    acc1[2] = MFMA16(ah, h2_, acc1[2]);                                       \
    acc1[3] = MFMA16(ah, h3_, acc1[3]);                                       \
    acc2[0] = MFMA16(al, h0_, acc2[0]);  acc2[0] = MFMA16(ah, l0_, acc2[0]);  \
    acc2[1] = MFMA16(al, h1_, acc2[1]);  acc2[1] = MFMA16(ah, l1_, acc2[1]);  \
    acc2[2] = MFMA16(al, h2_, acc2[2]);  acc2[2] = MFMA16(ah, l2_, acc2[2]);  \
    acc2[3] = MFMA16(al, h3_, acc2[3]);  acc2[3] = MFMA16(ah, l3_, acc2[3]);  \
} while (0)

#define BARRIER_KEEP(n) do {                                                  \
    __builtin_amdgcn_sched_barrier(0);                                        \
    asm volatile("s_waitcnt vmcnt(" #n ")" ::: "memory");                     \
    __builtin_amdgcn_sched_barrier(0);                                        \
    __builtin_amdgcn_s_barrier();                                             \
    __builtin_amdgcn_sched_barrier(0);                                        \
} while (0)

// full iter: stage B(c+2) into the 2-ahead buffer, load A(c+2), compute c.
// vmcnt(5) retires EXACTLY stage(c+1) (queue: st(c+1), A(c+1)x2, st(c+2),
// A(c+2)x2) -> the stage gets a full iteration of latency cover; the A
// pipeline is never force-drained (compiler's reg-dep waits handle A use).
#define ITER_FULL(c, ACa, ACb, ALa, ALb, BCUR, BNXT) do {                     \
    STAGE(BNXT, (c) + 2);                                                     \
    LOAD_A(ALa, ALb, (c) + 2);                                                \
    COMPC(BCUR, ACa, ACb);                                                    \
    BARRIER_KEEP(5);                                                          \
} while (0)

// ---------------------------------------------------------------------------
// Pass 1: partial logits. 512 blocks x 512 thr (8 waves = 8 M-tiles of 16
// tokens -> 128 tokens/block). Block (tg, kg) covers K-slice kg (16 chunks).
// All 8 waves consume the SAME staged B chunk; kg == XCD under %8 dispatch
// so each XCD keeps its 128 KB WF slice L2-resident.
// ---------------------------------------------------------------------------
__global__ __launch_bounds__(512, 4) void logits_kernel(
    const float* __restrict__ x,
    const _Float16* __restrict__ WF,
    float* __restrict__ P) {

    __shared__ _Float16 buf[3][4096];     // 3 x 8 KB triple-buffered B slab

    const int tid  = threadIdx.x;
    const int wq   = tid >> 6;            // wave = M-tile
    const int lane = tid & 63;
    const int kg   = (int)(blockIdx.x & 7);       // K-slice (512 d)
    const int tg   = (int)(blockIdx.x >> 3);      // token group (128 tokens)
    const int tok0 = tg * 128 + wq * 16;
    const int art  = lane & 15;           // token row within M-tile
    const int akg  = lane >> 4;           // k-group
    const int chunk0 = kg * 16;

    const float*    abase = x  + (size_t)(tok0 + art) * DIM + chunk0 * 32 + akg * 8;
    const _Float16* sbase = WF + (size_t)chunk0 * 4096 + (size_t)tid * 8;  // stage src

    v4f acc1[4], acc2[4];
    #pragma unroll
    for (int e4 = 0; e4 < 4; ++e4) { acc1[e4] = (v4f)0.0f; acc2[e4] = (v4f)0.0f; }

    v4f A0a, A0b, A1a, A1b, A2a, A2b;
    v8h ah, al;

    // prologue: st0, A0, A1, st1 (order keeps A0-use wait from draining st1);
    // vmcnt(5) retires exactly st0.
    STAGE(0, 0);
    LOAD_A(A0a, A0b, 0);
    LOAD_A(A1a, A1b, 1);
    STAGE(1, 1);
    BARRIER_KEEP(5);

    ITER_FULL(0,  A0a, A0b, A2a, A2b, 0, 2);
    ITER_FULL(1,  A1a, A1b, A0a, A0b, 1, 0);
    ITER_FULL(2,  A2a, A2b, A1a, A1b, 2, 1);
    ITER_FULL(3,  A0a, A0b, A2a, A2b, 0, 2);
    ITER_FULL(4,  A1a, A1b, A0a, A0b, 1, 0);
    ITER_FULL(5,  A2a, A2b, A1a, A1b, 2, 1);
    ITER_FULL(6,  A0a, A0b, A2a, A2b, 0, 2);
    ITER_FULL(7,  A1a, A1b, A0a, A0b, 1, 0);
    ITER_FULL(8,  A2a, A2b, A1a, A1b, 2, 1);
    ITER_FULL(9,  A0a, A0b, A2a, A2b, 0, 2);
    ITER_FULL(10, A1a, A1b, A0a, A0b, 1, 0);
    ITER_FULL(11, A2a, A2b, A1a, A1b, 2, 1);
    ITER_FULL(12, A0a, A0b, A2a, A2b, 0, 2);
    ITER_FULL(13, A1a, A1b, A0a, A0b, 1, 0);   // stages chunk 15 -> buf0, loads A(15)->A0
    // body(14): no stage/loads; vmcnt(2) retires st(15), keeps A(15)
    COMPC(2, A2a, A2b);
    BARRIER_KEEP(2);
    // body(15): last chunk
    COMPC(0, A0a, A0b);

    // write partial logits: C/D layout col=lane&15(expert), row=(lane>>4)*4+r
    const float inv2048 = 1.0f / 2048.0f;
    #pragma unroll
    for (int e4 = 0; e4 < 4; ++e4) {
        #pragma unroll
        for (int r = 0; r < 4; ++r) {
            float v = acc1[e4][r] + acc2[e4][r] * inv2048;
            P[((size_t)kg * TOKENS + tok0 + akg * 4 + r) * 64 + e4 * 16 + art] = v;
        }
    }
}

// ---------------------------------------------------------------------------
// Pass 2: logits = sum of 8 K-slice partials; top-2 + gates. 512 x 256.
// ---------------------------------------------------------------------------
__global__ __launch_bounds__(256) void reduce_topk_kernel(
    const float* __restrict__ P, float* __restrict__ out) {
    const int wq   = threadIdx.x >> 6;
    const int lane = threadIdx.x & 63;
    #pragma unroll
    for (int tt = 0; tt < 4; ++tt) {
        int gt = blockIdx.x * 16 + wq * 4 + tt;
        float v = 0.f;
        #pragma unroll
        for (int kg = 0; kg < 8; ++kg)
            v += P[((size_t)kg * TOKENS + gt) * 64 + lane];

        // argmax #1 (tie-break: smaller index, matching jax.lax.top_k)
        float bv = v; int bi = lane;
        #pragma unroll
        for (int off = 32; off >= 1; off >>= 1) {
            float ov = __shfl_xor(bv, off);
            int   oi = __shfl_xor(bi, off);
            if (ov > bv || (ov == bv && oi < bi)) { bv = ov; bi = oi; }
        }
        // argmax #2 (exclude bi)
        float v2 = (lane == bi) ? -FLT_MAX : v;
        float bv2 = v2; int bi2 = lane;
        #pragma unroll
        for (int off = 32; off >= 1; off >>= 1) {
            float ov = __shfl_xor(bv2, off);
            int   oi = __shfl_xor(bi2, off);
            if (ov > bv2 || (ov == bv2 && oi < bi2)) { bv2 = ov; bi2 = oi; }
        }

        if (lane == 0) {
            // top-2 renormalized softmax cancels: g0 = 1/(1+exp(l1-l0))
            float g0 = 1.0f / (1.0f + expf(bv2 - bv));
            out[gt]              = (float)bi;
            out[TOKENS + gt]     = (float)bi2;
            out[2 * TOKENS + gt] = g0;
            out[3 * TOKENS + gt] = 1.0f - g0;
        }
    }
}

extern "C" void kernel_launch(void* const* d_in, const int* in_sizes, int n_in,
                              void* d_out, int out_size, void* d_ws, size_t ws_size,
                              hipStream_t stream) {
    const float* x = (const float*)d_in[0];   // [8192, 4096] fp32
    const float* W = (const float*)d_in[1];   // [64, 4096] fp32
    float* out     = (float*)d_out;           // [4 * 8192] fp32
    _Float16* WF   = (_Float16*)d_ws;                     // 1 MB fragments
    float* P       = (float*)((char*)d_ws + (1 << 20));   // 16 MB partials

    prep_w_kernel<<<128, 256, 0, stream>>>(W, WF);
    logits_kernel<<<512, 512, 0, stream>>>(x, WF, P);
    reduce_topk_kernel<<<512, 256, 0, stream>>>(P, out);
}